// Round 9
// baseline (173.773 us; speedup 1.0000x reference)
//
#include <hip/hip_runtime.h>
#include <hip/hip_bf16.h>

#define D_ENC 512
#define NH 8
#define DHD 64
#define BB 8
#define SS 1024

typedef unsigned short u16;
typedef __attribute__((ext_vector_type(8))) short short8;
typedef __attribute__((ext_vector_type(4))) float floatx4;

// 0.125 (1/sqrt(DH)) * log2(e): flash softmax uses raw v_exp_f32 (2^x).
#define QSCALE 0.18033688011112042f

__device__ inline u16 f2bf(float f) {
    __hip_bfloat16 h = __float2bfloat16(f);
    return *reinterpret_cast<u16*>(&h);
}

// 16B-per-lane async global->LDS. LDS dest = wave-uniform base + lane*16.
__device__ inline void glds16(const u16* g, u16* l) {
    __builtin_amdgcn_global_load_lds(
        (const __attribute__((address_space(1))) void*)g,
        (__attribute__((address_space(3))) void*)l, 16, 0, 0);
}

// ---------------- Kernel 0: weight prep only (fp32 -> bf16, transposed) -----
// X conversion is folded into qkv_gemm's A-staging (saves a 113 MB HBM pass).
__global__ __launch_bounds__(256) void prep_w(
    const float* __restrict__ Wq, const float* __restrict__ Wk,
    const float* __restrict__ Wv, const float* __restrict__ Wo,
    u16* __restrict__ WqT, u16* __restrict__ WkT, u16* __restrict__ WvT,
    u16* __restrict__ WoT)
{
    int tid = blockIdx.x * 256 + threadIdx.x;
    const int WSZ = NH * D_ENC * DHD; // 262144
    if (tid < 3 * WSZ) {
        int wi = tid / WSZ, r = tid % WSZ;
        int d = r & 511;
        int e = (r >> 9) & 63;
        int h = r >> 15;
        const float* src = wi == 0 ? Wq : (wi == 1 ? Wk : Wv);
        u16* dst = wi == 0 ? WqT : (wi == 1 ? WkT : WvT);
        dst[r] = f2bf(src[h * (D_ENC * DHD) + d * DHD + e]);
    } else {
        int r = tid - 3 * WSZ;
        int d = r & 511, n = r >> 9;
        WoT[r] = f2bf(Wo[d * D_ENC + n]);
    }
}

// ---------------- Kernel 1: QKV projection, fused fp32->bf16 A-staging ------
// 128x64 tile, dbuf K-loop. A-tile: fp32 X global->VGPR->convert->ds_write
// (same swizzled layout as the DMA path). B-tile: glds16 DMA (bf16 weights).
// Loads for t+1 issue right after the barrier; convert+write after the MFMAs.
// smem (u16): [0,8192)=As0 [8192,16384)=As1 [16384,20480)=Bs0 [20480,24576)=Bs1
__global__ __launch_bounds__(256, 3) void qkv_gemm(
    const float* __restrict__ Qi, const float* __restrict__ Ki,
    const float* __restrict__ Vi,
    const u16* __restrict__ WqT, const u16* __restrict__ WkT,
    const u16* __restrict__ WvT,
    const float* __restrict__ bq, const float* __restrict__ bk,
    const float* __restrict__ bv,
    u16* __restrict__ Qh, u16* __restrict__ Kh, u16* __restrict__ VhT)
{
    const int proj = blockIdx.z;
    const float* X = proj == 0 ? Qi : (proj == 1 ? Ki : Vi);
    const u16* WT = proj == 0 ? WqT : (proj == 1 ? WkT : WvT);
    const float* bias = proj == 0 ? bq : (proj == 1 ? bk : bv);
    u16* out = proj == 0 ? Qh : (proj == 1 ? Kh : VhT);
    const float oscale = proj == 0 ? QSCALE : 1.0f;

    const int m0 = blockIdx.x * 128;
    const int n0 = blockIdx.y * 64;
    __shared__ __align__(16) u16 smem[24576];

    const int tid = threadIdx.x, lane = tid & 63, w = tid >> 6;
    const int q = lane >> 4, l15 = lane & 15;
    const int lr = lane >> 3;                 // row-within-8
    const int lc = (lane & 7) ^ (lr & 7);     // swizzled source chunk

    floatx4 acc[2][4] = {};
    float4 av[4][2];                          // staged A fp32 (4 rows x 8)

    // prologue: tile 0
    #pragma unroll
    for (int j = 0; j < 4; ++j) {
        int r = (j * 4 + w) * 8 + lr;
        const float4* src = (const float4*)&X[(size_t)(m0 + r) * D_ENC + lc * 8];
        av[j][0] = src[0]; av[j][1] = src[1];
    }
    #pragma unroll
    for (int j = 0; j < 2; ++j) {
        int r = (j * 4 + w) * 8 + lr;
        glds16(WT + (size_t)(n0 + r) * D_ENC + lc * 8,
               smem + 16384 + (j * 4 + w) * 512);
    }
    #pragma unroll
    for (int j = 0; j < 4; ++j) {
        int r = (j * 4 + w) * 8 + lr;
        u16 hv[8] = { f2bf(av[j][0].x), f2bf(av[j][0].y),
                      f2bf(av[j][0].z), f2bf(av[j][0].w),
                      f2bf(av[j][1].x), f2bf(av[j][1].y),
                      f2bf(av[j][1].z), f2bf(av[j][1].w) };
        *(uint4*)&smem[r * 64 + (lane & 7) * 8] =
            *reinterpret_cast<const uint4*>(hv);
    }

    for (int t = 0; t < 8; ++t) {
        __syncthreads();   // drains B DMA + A ds_writes for tile t
        if (t + 1 < 8) {
            const int d1 = (t + 1) * 64;
            #pragma unroll
            for (int j = 0; j < 4; ++j) {
                int r = (j * 4 + w) * 8 + lr;
                const float4* src =
                    (const float4*)&X[(size_t)(m0 + r) * D_ENC + d1 + lc * 8];
                av[j][0] = src[0]; av[j][1] = src[1];
            }
            u16* bd = smem + 16384 + ((t + 1) & 1) * 4096;
            #pragma unroll
            for (int j = 0; j < 2; ++j) {
                int r = (j * 4 + w) * 8 + lr;
                glds16(WT + (size_t)(n0 + r) * D_ENC + d1 + lc * 8,
                       bd + (j * 4 + w) * 512);
            }
        }
        const u16* as_ = smem + (t & 1) * 8192;
        const u16* bs_ = smem + 16384 + (t & 1) * 4096;
        #pragma unroll
        for (int ks = 0; ks < 2; ++ks) {
            const int co = ((ks * 4 + q) ^ (l15 & 7)) * 8;
            short8 a0 = *(const short8*)&as_[(32 * w + l15) * 64 + co];
            short8 a1 = *(const short8*)&as_[(32 * w + 16 + l15) * 64 + co];
            #pragma unroll
            for (int f = 0; f < 4; ++f) {
                short8 bf = *(const short8*)&bs_[(f * 16 + l15) * 64 + co];
                acc[0][f] = __builtin_amdgcn_mfma_f32_16x16x32_bf16(a0, bf, acc[0][f], 0, 0, 0);
                acc[1][f] = __builtin_amdgcn_mfma_f32_16x16x32_bf16(a1, bf, acc[1][f], 0, 0, 0);
            }
        }
        if (t + 1 < 8) {
            u16* ad = smem + ((t + 1) & 1) * 8192;
            #pragma unroll
            for (int j = 0; j < 4; ++j) {
                int r = (j * 4 + w) * 8 + lr;
                u16 hv[8] = { f2bf(av[j][0].x), f2bf(av[j][0].y),
                              f2bf(av[j][0].z), f2bf(av[j][0].w),
                              f2bf(av[j][1].x), f2bf(av[j][1].y),
                              f2bf(av[j][1].z), f2bf(av[j][1].w) };
                *(uint4*)&ad[r * 64 + (lane & 7) * 8] =
                    *reinterpret_cast<const uint4*>(hv);
            }
        }
    }

    const int b = m0 >> 10, sb = m0 & 1023, h = n0 >> 6;
    if (proj < 2) {
        u16* dst = out + ((size_t)(b * NH + h) * SS + sb) * DHD;
        #pragma unroll
        for (int i = 0; i < 2; ++i)
            #pragma unroll
            for (int f = 0; f < 4; ++f) {
                float bv_ = bias[n0 + f * 16 + l15];
                #pragma unroll
                for (int r = 0; r < 4; ++r)
                    dst[(32 * w + 16 * i + q * 4 + r) * DHD + f * 16 + l15] =
                        f2bf((acc[i][f][r] + bv_) * oscale);
            }
    } else {
        // V: transpose 128x64 -> [e][s] through LDS (Ts = smem, stride 136)
        __syncthreads();  // all waves done reading smem (proj uniform branch)
        #pragma unroll
        for (int i = 0; i < 2; ++i)
            #pragma unroll
            for (int f = 0; f < 4; ++f) {
                float bv_ = bias[n0 + f * 16 + l15];
                #pragma unroll
                for (int r = 0; r < 4; ++r)
                    smem[(f * 16 + l15) * 136 + 32 * w + 16 * i + q * 4 + r] =
                        f2bf(acc[i][f][r] + bv_);
            }
        __syncthreads();
        u16* dst = out + (size_t)(b * NH + h) * DHD * SS + sb;
        #pragma unroll
        for (int p2 = 0; p2 < 4; ++p2) {
            int c = (tid + 256 * p2) * 8;
            int e = c >> 7, s = c & 127;
            uint4 v = *(const uint4*)&smem[e * 136 + s];
            *(uint4*)&dst[(size_t)e * SS + s] = v;
        }
    }
}

// ---------------- Kernel 2: flash attention (round-5 proven) ----------------
// Flat grid 1024. bh = ((i>>3)&7)*8 + (i&7): all 16 s-tiles of one (b,h)
// on one XCD (i%8 heuristic) -> K/V stays in that XCD's L2.
// Qh pre-scaled by QSCALE (incl log2e); raw v_exp_f32 via builtin.
__global__ __launch_bounds__(256, 4) void flash_attn(
    const u16* __restrict__ Qh, const u16* __restrict__ Kh,
    const u16* __restrict__ VhT, u16* __restrict__ Xb)
{
    const int i = blockIdx.x;
    const int s0 = (i >> 6) * 64;
    const size_t bh = (size_t)(((i >> 3) & 7) * 8 + (i & 7));

    __shared__ __align__(16) u16 Ks[2][64 * 64], Vs[2][64 * 64], Ps[64 * 64];

    const int tid = threadIdx.x, lane = tid & 63, w = tid >> 6;
    const int q = lane >> 4, l15 = lane & 15;
    const int lr = lane >> 3, lc = (lane & 7) ^ (lr & 7);

    // Q B-frags: lane l15 = query s0+16w+l15; k = 32*ks + q*8 + j
    const u16* qrow = Qh + (bh * SS + s0 + 16 * w + l15) * DHD;
    short8 qb0 = *(const short8*)(qrow + q * 8);
    short8 qb1 = *(const short8*)(qrow + 32 + q * 8);

    const u16* kbase = Kh + bh * SS * DHD;
    const u16* vbase = VhT + bh * DHD * SS;

    #pragma unroll
    for (int j = 0; j < 2; ++j) {
        int r = (j * 4 + w) * 8 + lr;
        glds16(kbase + (size_t)r * DHD + lc * 8, Ks[0] + (j * 4 + w) * 512);
        glds16(vbase + (size_t)r * SS + lc * 8, Vs[0] + (j * 4 + w) * 512);
    }

    floatx4 O[4] = {};
    floatx4 L = {0.f, 0.f, 0.f, 0.f};
    const short8 ones = {16256, 16256, 16256, 16256,
                         16256, 16256, 16256, 16256};  // bf16 1.0

    for (int kt = 0; kt < SS / 64; ++kt) {
        __syncthreads();   // drains DMA for tile kt
        if (kt + 1 < SS / 64) {
            const int k1 = (kt + 1) * 64;
            u16* kd = Ks[(kt + 1) & 1];
            u16* vd = Vs[(kt + 1) & 1];
            #pragma unroll
            for (int j = 0; j < 2; ++j) {
                int r = (j * 4 + w) * 8 + lr;
                glds16(kbase + (size_t)(k1 + r) * DHD + lc * 8,
                       kd + (j * 4 + w) * 512);
                glds16(vbase + (size_t)r * SS + k1 + lc * 8,
                       vd + (j * 4 + w) * 512);
            }
        }
        const u16* ks_ = Ks[kt & 1];
        const u16* vs_ = Vs[kt & 1];

        // S^T[key][query]
        floatx4 sacc[4] = {};
        #pragma unroll
        for (int f = 0; f < 4; ++f) {
            const int co0 = (q ^ (l15 & 7)) * 8;
            const int co1 = ((4 + q) ^ (l15 & 7)) * 8;
            short8 ka0 = *(const short8*)&ks_[(f * 16 + l15) * 64 + co0];
            short8 ka1 = *(const short8*)&ks_[(f * 16 + l15) * 64 + co1];
            sacc[f] = __builtin_amdgcn_mfma_f32_16x16x32_bf16(ka0, qb0, sacc[f], 0, 0, 0);
            sacc[f] = __builtin_amdgcn_mfma_f32_16x16x32_bf16(ka1, qb1, sacc[f], 0, 0, 0);
        }

        // P = 2^(S^T) -> 4 packed b64 LDS writes (wave-private rows)
        #pragma unroll
        for (int f = 0; f < 4; ++f) {
            ushort4 pk;
            pk.x = f2bf(__builtin_amdgcn_exp2f(sacc[f][0]));
            pk.y = f2bf(__builtin_amdgcn_exp2f(sacc[f][1]));
            pk.z = f2bf(__builtin_amdgcn_exp2f(sacc[f][2]));
            pk.w = f2bf(__builtin_amdgcn_exp2f(sacc[f][3]));
            const int chunk = (2 * f + (q >> 1)) ^ (l15 & 7);
            *(ushort4*)&Ps[(16 * w + l15) * 64 + chunk * 8 + (q & 1) * 4] = pk;
        }

        // O += P V ; L += P @ ones
        #pragma unroll
        for (int ks = 0; ks < 2; ++ks) {
            const int co = ((ks * 4 + q) ^ (l15 & 7)) * 8;
            short8 pa = *(const short8*)&Ps[(16 * w + l15) * 64 + co];
            L = __builtin_amdgcn_mfma_f32_16x16x32_bf16(pa, ones, L, 0, 0, 0);
            #pragma unroll
            for (int f = 0; f < 4; ++f) {
                short8 vb = *(const short8*)&vs_[(f * 16 + l15) * 64 + co];
                O[f] = __builtin_amdgcn_mfma_f32_16x16x32_bf16(pa, vb, O[f], 0, 0, 0);
            }
        }
    }

    u16* dst = Xb + (bh * SS + s0) * DHD;
    #pragma unroll
    for (int f = 0; f < 4; ++f)
        #pragma unroll
        for (int r = 0; r < 4; ++r)
            dst[(16 * w + q * 4 + r) * DHD + f * 16 + l15] =
                f2bf(O[f][r] / L[r]);
}

// ---------------- Kernel 3: output projection, dbuf K-loop ------------------
__global__ __launch_bounds__(256, 3) void out_gemm(
    const u16* __restrict__ X, const u16* __restrict__ WT,
    const float* __restrict__ bias, float* __restrict__ out)
{
    const int m0 = blockIdx.x * 128;
    const int n0 = blockIdx.y * 64;
    __shared__ __align__(16) u16 smem[24576];

    const int tid = threadIdx.x, lane = tid & 63, w = tid >> 6;
    const int q = lane >> 4, l15 = lane & 15;
    const int lr = lane >> 3, lc = (lane & 7) ^ (lr & 7);

    floatx4 acc[2][4] = {};

    #pragma unroll
    for (int j = 0; j < 4; ++j) {
        int r = (j * 4 + w) * 8 + lr;
        glds16(X + (size_t)(m0 + r) * D_ENC + lc * 8, smem + (j * 4 + w) * 512);
    }
    #pragma unroll
    for (int j = 0; j < 2; ++j) {
        int r = (j * 4 + w) * 8 + lr;
        glds16(WT + (size_t)(n0 + r) * D_ENC + lc * 8,
               smem + 16384 + (j * 4 + w) * 512);
    }

    for (int t = 0; t < 8; ++t) {
        __syncthreads();
        if (t + 1 < 8) {
            const int d1 = (t + 1) * 64;
            u16* ad = smem + ((t + 1) & 1) * 8192;
            u16* bd = smem + 16384 + ((t + 1) & 1) * 4096;
            #pragma unroll
            for (int j = 0; j < 4; ++j) {
                int r = (j * 4 + w) * 8 + lr;
                glds16(X + (size_t)(m0 + r) * D_ENC + d1 + lc * 8,
                       ad + (j * 4 + w) * 512);
            }
            #pragma unroll
            for (int j = 0; j < 2; ++j) {
                int r = (j * 4 + w) * 8 + lr;
                glds16(WT + (size_t)(n0 + r) * D_ENC + d1 + lc * 8,
                       bd + (j * 4 + w) * 512);
            }
        }
        const u16* as_ = smem + (t & 1) * 8192;
        const u16* bs_ = smem + 16384 + (t & 1) * 4096;
        #pragma unroll
        for (int ks = 0; ks < 2; ++ks) {
            const int co = ((ks * 4 + q) ^ (l15 & 7)) * 8;
            short8 a0 = *(const short8*)&as_[(32 * w + l15) * 64 + co];
            short8 a1 = *(const short8*)&as_[(32 * w + 16 + l15) * 64 + co];
            #pragma unroll
            for (int f = 0; f < 4; ++f) {
                short8 bf = *(const short8*)&bs_[(f * 16 + l15) * 64 + co];
                acc[0][f] = __builtin_amdgcn_mfma_f32_16x16x32_bf16(a0, bf, acc[0][f], 0, 0, 0);
                acc[1][f] = __builtin_amdgcn_mfma_f32_16x16x32_bf16(a1, bf, acc[1][f], 0, 0, 0);
            }
        }
    }
    #pragma unroll
    for (int i = 0; i < 2; ++i)
        #pragma unroll
        for (int f = 0; f < 4; ++f) {
            float bv_ = bias[n0 + f * 16 + l15];
            #pragma unroll
            for (int r = 0; r < 4; ++r)
                out[(size_t)(m0 + 32 * w + 16 * i + q * 4 + r) * D_ENC +
                    n0 + f * 16 + l15] = acc[i][f][r] + bv_;
        }
}

extern "C" void kernel_launch(void* const* d_in, const int* in_sizes, int n_in,
                              void* d_out, int out_size, void* d_ws, size_t ws_size,
                              hipStream_t stream)
{
    const float* Q  = (const float*)d_in[0];
    const float* K  = (const float*)d_in[1];
    const float* V  = (const float*)d_in[2];
    const float* Wq = (const float*)d_in[3];
    const float* bq = (const float*)d_in[4];
    const float* Wk = (const float*)d_in[5];
    const float* bk = (const float*)d_in[6];
    const float* Wv = (const float*)d_in[7];
    const float* bv = (const float*)d_in[8];
    const float* Wo = (const float*)d_in[9];
    const float* bo = (const float*)d_in[10];
    float* out = (float*)d_out;

    char* ws = (char*)d_ws;
    u16* WqT = (u16*)(ws + 0);
    u16* WkT = (u16*)(ws + 524288);
    u16* WvT = (u16*)(ws + 1048576);
    u16* WoT = (u16*)(ws + 1572864);
    u16* Qh  = (u16*)(ws + 2097152);   // 8 MB
    u16* Kh  = (u16*)(ws + 10485760);  // 8 MB
    u16* VhT = (u16*)(ws + 18874368);  // 8 MB
    u16* Xb  = (u16*)(ws + 27262976);  // 8 MB (total 33.6 MB)

    hipLaunchKernelGGL(prep_w, dim3(4096), dim3(256), 0, stream,
                       Wq, Wk, Wv, Wo, WqT, WkT, WvT, WoT);
    hipLaunchKernelGGL(qkv_gemm, dim3(64, 8, 3), dim3(256), 0, stream,
                       Q, K, V, WqT, WkT, WvT, bq, bk, bv, Qh, Kh, VhT);
    hipLaunchKernelGGL(flash_attn, dim3(1024), dim3(256), 0, stream,
                       Qh, Kh, VhT, Xb);
    hipLaunchKernelGGL(out_gemm, dim3(64, 8), dim3(256), 0, stream,
                       Xb, WoT, bo, out);
}

// Round 10
// 163.705 us; speedup vs baseline: 1.0615x; 1.0615x over previous
//
#include <hip/hip_runtime.h>
#include <hip/hip_bf16.h>

#define D_ENC 512
#define NH 8
#define DHD 64
#define BB 8
#define SS 1024

typedef unsigned short u16;
typedef __attribute__((ext_vector_type(8))) short short8;
typedef __attribute__((ext_vector_type(4))) float floatx4;

// 0.125 (1/sqrt(DH)) * log2(e): flash softmax uses raw v_exp_f32 (2^x).
#define QSCALE 0.18033688011112042f

__device__ inline u16 f2bf(float f) {
    __hip_bfloat16 h = __float2bfloat16(f);
    return *reinterpret_cast<u16*>(&h);
}

// 16B-per-lane async global->LDS. LDS dest = wave-uniform base + lane*16.
__device__ inline void glds16(const u16* g, u16* l) {
    __builtin_amdgcn_global_load_lds(
        (const __attribute__((address_space(1))) void*)g,
        (__attribute__((address_space(3))) void*)l, 16, 0, 0);
}

// ---------------- Kernel 0: fused prep (weights transpose + X convert) ------
__global__ __launch_bounds__(256) void prep_all(
    const float* __restrict__ Wq, const float* __restrict__ Wk,
    const float* __restrict__ Wv, const float* __restrict__ Wo,
    const float* __restrict__ Q, const float* __restrict__ K,
    const float* __restrict__ V,
    u16* __restrict__ WqT, u16* __restrict__ WkT, u16* __restrict__ WvT,
    u16* __restrict__ WoT, u16* __restrict__ Xbf)
{
    int bx = blockIdx.x;
    if (bx < 4096) {
        int tid = bx * 256 + threadIdx.x;
        const int WSZ = NH * D_ENC * DHD; // 262144
        if (tid < 3 * WSZ) {
            int wi = tid / WSZ, r = tid % WSZ;
            int d = r & 511;
            int e = (r >> 9) & 63;
            int h = r >> 15;
            const float* src = wi == 0 ? Wq : (wi == 1 ? Wk : Wv);
            u16* dst = wi == 0 ? WqT : (wi == 1 ? WkT : WvT);
            dst[r] = f2bf(src[h * (D_ENC * DHD) + d * DHD + e]);
        } else {
            int r = tid - 3 * WSZ;
            int d = r & 511, n = r >> 9;
            WoT[r] = f2bf(Wo[d * D_ENC + n]);
        }
    } else {
        int t = (bx - 4096) * 256 + threadIdx.x;   // 8 els each
        int p = t / 524288, i = t % 524288;
        const float* src = p == 0 ? Q : (p == 1 ? K : V);
        const float4* s4 = reinterpret_cast<const float4*>(src) + (size_t)i * 2;
        float4 a = s4[0], b = s4[1];
        u16 hv[8] = { f2bf(a.x), f2bf(a.y), f2bf(a.z), f2bf(a.w),
                      f2bf(b.x), f2bf(b.y), f2bf(b.z), f2bf(b.w) };
        *reinterpret_cast<uint4*>(Xbf + (size_t)t * 8) =
            *reinterpret_cast<const uint4*>(hv);
    }
}

// ---------------- Kernel 1: QKV projection, 128x64 tile, dbuf K-loop --------
// Flat grid 1536, XCD-swizzled: mp=(i&7)|((i>>6)<<3) selects (m,proj);
// head=(i>>3)&7. The 8 head-blocks sharing one 128-row A-slab sit at indices
// congruent mod 8 -> same XCD -> slab fetched once into that XCD's L2.
// smem (u16): [0,8192)=As0 [8192,16384)=As1 [16384,20480)=Bs0 [20480,24576)=Bs1
__global__ __launch_bounds__(256, 3) void qkv_gemm(
    const u16* __restrict__ Xbf,
    const u16* __restrict__ WqT, const u16* __restrict__ WkT,
    const u16* __restrict__ WvT,
    const float* __restrict__ bq, const float* __restrict__ bk,
    const float* __restrict__ bv,
    u16* __restrict__ Qh, u16* __restrict__ Kh, u16* __restrict__ VhT)
{
    const int i = blockIdx.x;                  // 0..1535
    const int mp = (i & 7) | ((i >> 6) << 3);  // 0..191
    const int m0 = (mp & 63) * 128;
    const int proj = mp >> 6;
    const int n0 = ((i >> 3) & 7) * 64;

    const u16* X = Xbf + (size_t)proj * (BB * SS * D_ENC);
    const u16* WT = proj == 0 ? WqT : (proj == 1 ? WkT : WvT);
    const float* bias = proj == 0 ? bq : (proj == 1 ? bk : bv);
    u16* out = proj == 0 ? Qh : (proj == 1 ? Kh : VhT);
    const float oscale = proj == 0 ? QSCALE : 1.0f;

    __shared__ __align__(16) u16 smem[24576];

    const int tid = threadIdx.x, lane = tid & 63, w = tid >> 6;
    const int q = lane >> 4, l15 = lane & 15;
    const int lr = lane >> 3;                 // row-within-8
    const int lc = (lane & 7) ^ (lr & 7);     // swizzled source chunk

    floatx4 acc[2][4] = {};

    // prologue: stage tile 0
    #pragma unroll
    for (int j = 0; j < 4; ++j) {
        int r = (j * 4 + w) * 8 + lr;
        glds16(X + (size_t)(m0 + r) * D_ENC + lc * 8, smem + (j * 4 + w) * 512);
    }
    #pragma unroll
    for (int j = 0; j < 2; ++j) {
        int r = (j * 4 + w) * 8 + lr;
        glds16(WT + (size_t)(n0 + r) * D_ENC + lc * 8,
               smem + 16384 + (j * 4 + w) * 512);
    }

    for (int t = 0; t < 8; ++t) {
        __syncthreads();   // drains tile t's DMA; prior compute done
        if (t + 1 < 8) {
            const int d1 = (t + 1) * 64;
            u16* ad = smem + ((t + 1) & 1) * 8192;
            u16* bd = smem + 16384 + ((t + 1) & 1) * 4096;
            #pragma unroll
            for (int j = 0; j < 4; ++j) {
                int r = (j * 4 + w) * 8 + lr;
                glds16(X + (size_t)(m0 + r) * D_ENC + d1 + lc * 8,
                       ad + (j * 4 + w) * 512);
            }
            #pragma unroll
            for (int j = 0; j < 2; ++j) {
                int r = (j * 4 + w) * 8 + lr;
                glds16(WT + (size_t)(n0 + r) * D_ENC + d1 + lc * 8,
                       bd + (j * 4 + w) * 512);
            }
        }
        const u16* as_ = smem + (t & 1) * 8192;
        const u16* bs_ = smem + 16384 + (t & 1) * 4096;
        #pragma unroll
        for (int ks = 0; ks < 2; ++ks) {
            const int co = ((ks * 4 + q) ^ (l15 & 7)) * 8;
            short8 a0 = *(const short8*)&as_[(32 * w + l15) * 64 + co];
            short8 a1 = *(const short8*)&as_[(32 * w + 16 + l15) * 64 + co];
            #pragma unroll
            for (int f = 0; f < 4; ++f) {
                short8 bf = *(const short8*)&bs_[(f * 16 + l15) * 64 + co];
                acc[0][f] = __builtin_amdgcn_mfma_f32_16x16x32_bf16(a0, bf, acc[0][f], 0, 0, 0);
                acc[1][f] = __builtin_amdgcn_mfma_f32_16x16x32_bf16(a1, bf, acc[1][f], 0, 0, 0);
            }
        }
    }

    const int b = m0 >> 10, sb = m0 & 1023, h = n0 >> 6;
    if (proj < 2) {
        u16* dst = out + ((size_t)(b * NH + h) * SS + sb) * DHD;
        #pragma unroll
        for (int i2 = 0; i2 < 2; ++i2)
            #pragma unroll
            for (int f = 0; f < 4; ++f) {
                float bv_ = bias[n0 + f * 16 + l15];
                #pragma unroll
                for (int r = 0; r < 4; ++r)
                    dst[(32 * w + 16 * i2 + q * 4 + r) * DHD + f * 16 + l15] =
                        f2bf((acc[i2][f][r] + bv_) * oscale);
            }
    } else {
        // V: transpose 128x64 -> [e][s] through LDS (Ts = smem, stride 136)
        __syncthreads();  // all waves done reading smem (proj uniform branch)
        #pragma unroll
        for (int i2 = 0; i2 < 2; ++i2)
            #pragma unroll
            for (int f = 0; f < 4; ++f) {
                float bv_ = bias[n0 + f * 16 + l15];
                #pragma unroll
                for (int r = 0; r < 4; ++r)
                    smem[(f * 16 + l15) * 136 + 32 * w + 16 * i2 + q * 4 + r] =
                        f2bf(acc[i2][f][r] + bv_);
            }
        __syncthreads();
        u16* dst = out + (size_t)(b * NH + h) * DHD * SS + sb;
        #pragma unroll
        for (int p2 = 0; p2 < 4; ++p2) {
            int c = (tid + 256 * p2) * 8;
            int e = c >> 7, s = c & 127;
            uint4 v = *(const uint4*)&smem[e * 136 + s];
            *(uint4*)&dst[(size_t)e * SS + s] = v;
        }
    }
}

// ---------------- Kernel 2: flash attention (round-5 proven) ----------------
// Flat grid 1024. bh = ((i>>3)&7)*8 + (i&7): all 16 s-tiles of one (b,h)
// on one XCD (i%8 heuristic) -> K/V stays in that XCD's L2.
// Qh pre-scaled by QSCALE (incl log2e); raw v_exp_f32 via builtin.
__global__ __launch_bounds__(256, 4) void flash_attn(
    const u16* __restrict__ Qh, const u16* __restrict__ Kh,
    const u16* __restrict__ VhT, u16* __restrict__ Xb)
{
    const int i = blockIdx.x;
    const int s0 = (i >> 6) * 64;
    const size_t bh = (size_t)(((i >> 3) & 7) * 8 + (i & 7));

    __shared__ __align__(16) u16 Ks[2][64 * 64], Vs[2][64 * 64], Ps[64 * 64];

    const int tid = threadIdx.x, lane = tid & 63, w = tid >> 6;
    const int q = lane >> 4, l15 = lane & 15;
    const int lr = lane >> 3, lc = (lane & 7) ^ (lr & 7);

    // Q B-frags: lane l15 = query s0+16w+l15; k = 32*ks + q*8 + j
    const u16* qrow = Qh + (bh * SS + s0 + 16 * w + l15) * DHD;
    short8 qb0 = *(const short8*)(qrow + q * 8);
    short8 qb1 = *(const short8*)(qrow + 32 + q * 8);

    const u16* kbase = Kh + bh * SS * DHD;
    const u16* vbase = VhT + bh * DHD * SS;

    #pragma unroll
    for (int j = 0; j < 2; ++j) {
        int r = (j * 4 + w) * 8 + lr;
        glds16(kbase + (size_t)r * DHD + lc * 8, Ks[0] + (j * 4 + w) * 512);
        glds16(vbase + (size_t)r * SS + lc * 8, Vs[0] + (j * 4 + w) * 512);
    }

    floatx4 O[4] = {};
    floatx4 L = {0.f, 0.f, 0.f, 0.f};
    const short8 ones = {16256, 16256, 16256, 16256,
                         16256, 16256, 16256, 16256};  // bf16 1.0

    for (int kt = 0; kt < SS / 64; ++kt) {
        __syncthreads();   // drains DMA for tile kt
        if (kt + 1 < SS / 64) {
            const int k1 = (kt + 1) * 64;
            u16* kd = Ks[(kt + 1) & 1];
            u16* vd = Vs[(kt + 1) & 1];
            #pragma unroll
            for (int j = 0; j < 2; ++j) {
                int r = (j * 4 + w) * 8 + lr;
                glds16(kbase + (size_t)(k1 + r) * DHD + lc * 8,
                       kd + (j * 4 + w) * 512);
                glds16(vbase + (size_t)r * SS + k1 + lc * 8,
                       vd + (j * 4 + w) * 512);
            }
        }
        const u16* ks_ = Ks[kt & 1];
        const u16* vs_ = Vs[kt & 1];

        // S^T[key][query]
        floatx4 sacc[4] = {};
        #pragma unroll
        for (int f = 0; f < 4; ++f) {
            const int co0 = (q ^ (l15 & 7)) * 8;
            const int co1 = ((4 + q) ^ (l15 & 7)) * 8;
            short8 ka0 = *(const short8*)&ks_[(f * 16 + l15) * 64 + co0];
            short8 ka1 = *(const short8*)&ks_[(f * 16 + l15) * 64 + co1];
            sacc[f] = __builtin_amdgcn_mfma_f32_16x16x32_bf16(ka0, qb0, sacc[f], 0, 0, 0);
            sacc[f] = __builtin_amdgcn_mfma_f32_16x16x32_bf16(ka1, qb1, sacc[f], 0, 0, 0);
        }

        // P = 2^(S^T) -> 4 packed b64 LDS writes (wave-private rows)
        #pragma unroll
        for (int f = 0; f < 4; ++f) {
            ushort4 pk;
            pk.x = f2bf(__builtin_amdgcn_exp2f(sacc[f][0]));
            pk.y = f2bf(__builtin_amdgcn_exp2f(sacc[f][1]));
            pk.z = f2bf(__builtin_amdgcn_exp2f(sacc[f][2]));
            pk.w = f2bf(__builtin_amdgcn_exp2f(sacc[f][3]));
            const int chunk = (2 * f + (q >> 1)) ^ (l15 & 7);
            *(ushort4*)&Ps[(16 * w + l15) * 64 + chunk * 8 + (q & 1) * 4] = pk;
        }

        // O += P V ; L += P @ ones
        #pragma unroll
        for (int ks = 0; ks < 2; ++ks) {
            const int co = ((ks * 4 + q) ^ (l15 & 7)) * 8;
            short8 pa = *(const short8*)&Ps[(16 * w + l15) * 64 + co];
            L = __builtin_amdgcn_mfma_f32_16x16x32_bf16(pa, ones, L, 0, 0, 0);
            #pragma unroll
            for (int f = 0; f < 4; ++f) {
                short8 vb = *(const short8*)&vs_[(f * 16 + l15) * 64 + co];
                O[f] = __builtin_amdgcn_mfma_f32_16x16x32_bf16(pa, vb, O[f], 0, 0, 0);
            }
        }
    }

    u16* dst = Xb + (bh * SS + s0) * DHD;
    #pragma unroll
    for (int f = 0; f < 4; ++f)
        #pragma unroll
        for (int r = 0; r < 4; ++r)
            dst[(16 * w + q * 4 + r) * DHD + f * 16 + l15] =
                f2bf(O[f][r] / L[r]);
}

// ---------------- Kernel 3: output projection, dbuf K-loop ------------------
// Flat grid 512, XCD-swizzled: the 8 n-blocks sharing one A-slab land on the
// same XCD (indices congruent mod 8).
__global__ __launch_bounds__(256, 3) void out_gemm(
    const u16* __restrict__ X, const u16* __restrict__ WT,
    const float* __restrict__ bias, float* __restrict__ out)
{
    const int i = blockIdx.x;                         // 0..511
    const int m0 = ((i & 7) | ((i >> 6) << 3)) * 128; // 64 m-slabs
    const int n0 = ((i >> 3) & 7) * 64;
    __shared__ __align__(16) u16 smem[24576];

    const int tid = threadIdx.x, lane = tid & 63, w = tid >> 6;
    const int q = lane >> 4, l15 = lane & 15;
    const int lr = lane >> 3, lc = (lane & 7) ^ (lr & 7);

    floatx4 acc[2][4] = {};

    #pragma unroll
    for (int j = 0; j < 4; ++j) {
        int r = (j * 4 + w) * 8 + lr;
        glds16(X + (size_t)(m0 + r) * D_ENC + lc * 8, smem + (j * 4 + w) * 512);
    }
    #pragma unroll
    for (int j = 0; j < 2; ++j) {
        int r = (j * 4 + w) * 8 + lr;
        glds16(WT + (size_t)(n0 + r) * D_ENC + lc * 8,
               smem + 16384 + (j * 4 + w) * 512);
    }

    for (int t = 0; t < 8; ++t) {
        __syncthreads();
        if (t + 1 < 8) {
            const int d1 = (t + 1) * 64;
            u16* ad = smem + ((t + 1) & 1) * 8192;
            u16* bd = smem + 16384 + ((t + 1) & 1) * 4096;
            #pragma unroll
            for (int j = 0; j < 4; ++j) {
                int r = (j * 4 + w) * 8 + lr;
                glds16(X + (size_t)(m0 + r) * D_ENC + d1 + lc * 8,
                       ad + (j * 4 + w) * 512);
            }
            #pragma unroll
            for (int j = 0; j < 2; ++j) {
                int r = (j * 4 + w) * 8 + lr;
                glds16(WT + (size_t)(n0 + r) * D_ENC + d1 + lc * 8,
                       bd + (j * 4 + w) * 512);
            }
        }
        const u16* as_ = smem + (t & 1) * 8192;
        const u16* bs_ = smem + 16384 + (t & 1) * 4096;
        #pragma unroll
        for (int ks = 0; ks < 2; ++ks) {
            const int co = ((ks * 4 + q) ^ (l15 & 7)) * 8;
            short8 a0 = *(const short8*)&as_[(32 * w + l15) * 64 + co];
            short8 a1 = *(const short8*)&as_[(32 * w + 16 + l15) * 64 + co];
            #pragma unroll
            for (int f = 0; f < 4; ++f) {
                short8 bf = *(const short8*)&bs_[(f * 16 + l15) * 64 + co];
                acc[0][f] = __builtin_amdgcn_mfma_f32_16x16x32_bf16(a0, bf, acc[0][f], 0, 0, 0);
                acc[1][f] = __builtin_amdgcn_mfma_f32_16x16x32_bf16(a1, bf, acc[1][f], 0, 0, 0);
            }
        }
    }
    #pragma unroll
    for (int i2 = 0; i2 < 2; ++i2)
        #pragma unroll
        for (int f = 0; f < 4; ++f) {
            float bv_ = bias[n0 + f * 16 + l15];
            #pragma unroll
            for (int r = 0; r < 4; ++r)
                out[(size_t)(m0 + 32 * w + 16 * i2 + q * 4 + r) * D_ENC +
                    n0 + f * 16 + l15] = acc[i2][f][r] + bv_;
        }
}

extern "C" void kernel_launch(void* const* d_in, const int* in_sizes, int n_in,
                              void* d_out, int out_size, void* d_ws, size_t ws_size,
                              hipStream_t stream)
{
    const float* Q  = (const float*)d_in[0];
    const float* K  = (const float*)d_in[1];
    const float* V  = (const float*)d_in[2];
    const float* Wq = (const float*)d_in[3];
    const float* bq = (const float*)d_in[4];
    const float* Wk = (const float*)d_in[5];
    const float* bk = (const float*)d_in[6];
    const float* Wv = (const float*)d_in[7];
    const float* bv = (const float*)d_in[8];
    const float* Wo = (const float*)d_in[9];
    const float* bo = (const float*)d_in[10];
    float* out = (float*)d_out;

    char* ws = (char*)d_ws;
    u16* WqT = (u16*)(ws + 0);
    u16* WkT = (u16*)(ws + 524288);
    u16* WvT = (u16*)(ws + 1048576);
    u16* WoT = (u16*)(ws + 1572864);
    u16* Xbf = (u16*)(ws + 2097152);   // [3][4194304] (25.2 MB)
    u16* Xb  = (u16*)(ws + 2097152);   // over Xbf[0] (dead when flash runs)
    u16* Qh  = (u16*)(ws + 27262976);  // 8 MB
    u16* Kh  = (u16*)(ws + 35651584);  // 8 MB
    u16* VhT = (u16*)(ws + 44040192);  // 8 MB

    hipLaunchKernelGGL(prep_all, dim3(10240), dim3(256), 0, stream,
                       Wq, Wk, Wv, Wo, Q, K, V, WqT, WkT, WvT, WoT, Xbf);
    hipLaunchKernelGGL(qkv_gemm, dim3(1536), dim3(256), 0, stream,
                       Xbf, WqT, WkT, WvT, bq, bk, bv, Qh, Kh, VhT);
    hipLaunchKernelGGL(flash_attn, dim3(1024), dim3(256), 0, stream,
                       Qh, Kh, VhT, Xb);
    hipLaunchKernelGGL(out_gemm, dim3(512), dim3(256), 0, stream,
                       Xb, WoT, bo, out);
}